// Round 14
// baseline (266.774 us; speedup 1.0000x reference)
//
#include <hip/hip_runtime.h>
#include <hip/hip_fp16.h>
#include <math.h>

#define Bq 4
#define Nq 512
#define Dq 4
#define Hq 256

typedef _Float16 f16x8 __attribute__((ext_vector_type(8)));
typedef float f32x4 __attribute__((ext_vector_type(4)));

// packed fp16 add + relu on 8 halves (v_pk_add_f16 + v_pk_max_f16)
__device__ __forceinline__ f16x8 hadd_relu(f16x8 u, f16x8 v) {
    f16x8 s = u + v;
    const f16x8 z = (f16x8)(_Float16)0.0f;
    return __builtin_elementwise_max(s, z);
}

__device__ __forceinline__ uint4 cvt8h(const float* p) {
    union { __half h[8]; uint4 u; } r;
#pragma unroll
    for (int i = 0; i < 8; ++i) r.h[i] = __float2half(p[i]);
    return r.u;
}

// ---------------- kernel 1: fused prep (U/V + tail-weight transpose) ------
// blocks 0..255: U/V for 8 rows each.
// blocks 256..303: coalesced 64x64 LDS-tile transpose of Wn1/Wn2/Wo1[4:].
// block 256 also zeroes the 128 group counters (ws is 0xAA-poisoned per run).
__global__ __launch_bounds__(256) void prep_all(
    const float* __restrict__ x, const float* __restrict__ We1,
    const float* __restrict__ be1, __half* __restrict__ U, __half* __restrict__ V,
    const float* __restrict__ Wn1, const float* __restrict__ Wn2,
    const float* __restrict__ Wo1, __half* __restrict__ Wt16,
    int* __restrict__ counters) {
    const int bid = blockIdx.x;
    const int t = threadIdx.x;
    if (bid < 256) {
        const float w0 = We1[0 * 256 + t], w1 = We1[1 * 256 + t];
        const float w2 = We1[2 * 256 + t], w3 = We1[3 * 256 + t];
        const float w4 = We1[4 * 256 + t], w5 = We1[5 * 256 + t];
        const float w6 = We1[6 * 256 + t], w7 = We1[7 * 256 + t];
        const float bv = be1[t];
#pragma unroll
        for (int r = 0; r < 8; ++r) {
            const int row = bid * 8 + r;
            const float* xp = x + row * Dq;
            const float x0 = xp[0], x1 = xp[1], x2 = xp[2], x3 = xp[3];
            float u = bv;
            u = fmaf(x0, w0, u); u = fmaf(x1, w1, u);
            u = fmaf(x2, w2, u); u = fmaf(x3, w3, u);
            float v = x0 * w4;
            v = fmaf(x1, w5, v); v = fmaf(x2, w6, v); v = fmaf(x3, w7, v);
            U[(size_t)row * Hq + t] = __float2half(u);
            V[(size_t)row * Hq + t] = __float2half(v);
        }
    } else {
        if (bid == 256 && t < 128) counters[t] = 0;
        __shared__ float ld[64][65];       // padded: stride-65 reads conflict-free
        const int tid = bid - 256;         // 0..47
        const int mat = tid >> 4;          // 0..2
        const int tile = tid & 15;         // 4x4 tiles of 64x64
        const int k0 = (tile >> 2) * 64;
        const int n0 = (tile & 3) * 64;
        const float* W = (mat == 0) ? Wn1 : (mat == 1) ? Wn2 : (Wo1 + 4 * 256);
        const int rr = t >> 6;             // 0..3
        const int cc = t & 63;             // 0..63
#pragma unroll
        for (int r = 0; r < 16; ++r) {
            const int row = r * 4 + rr;
            ld[row][cc] = W[(size_t)(k0 + row) * 256 + n0 + cc];  // coalesced read
        }
        __syncthreads();
#pragma unroll
        for (int r = 0; r < 16; ++r) {
            const int nrow = r * 4 + rr;
            Wt16[((size_t)mat * 256 + n0 + nrow) * 256 + k0 + cc] =
                __float2half(ld[cc][nrow]);
        }
    }
}

// ---------------- kernel 2: edge GEMM + aggregation + FUSED tail ----------
// Edge phase = R7/R13 verbatim (plateaued 145 us). After the aggws store,
// each block tickets its (b,jt) group (4 h-quarter blocks); the 4th
// finisher — which knows the group's full 256-h agg rows are complete —
// acquires (threadfence) and runs the R11 MFMA tail for its 16 nodes,
// reusing its LDS. Removes the tail dispatch boundary + overlaps tail
// compute under edge stragglers. Device-scope atomicAdd [m20] +
// __threadfence per Guideline 16.
__global__ __launch_bounds__(256, 2) void edge_gemm(
    const __half* __restrict__ U, const __half* __restrict__ V,
    const float* __restrict__ We2, const float* __restrict__ be2,
    const float* __restrict__ adj, float* __restrict__ aggws,
    const float* __restrict__ x, const __half* __restrict__ Wt16,
    const float* __restrict__ bn1, const float* __restrict__ bn2,
    const float* __restrict__ Wo1, const float* __restrict__ bo1,
    const float* __restrict__ Wo, const float* __restrict__ bo,
    float* __restrict__ out, int* __restrict__ counters) {
    __shared__ __align__(16) char smem[59392];
    __shared__ int ticket_s;
    __half* Wt = (__half*)smem;
    __half* Us = (__half*)(smem + 32768);
    __half* Vs = (__half*)(smem + 40960);      // [2][16][256] halves
    float* adjs = (float*)(smem + 57344);      // [2][16][16]
    float* red = (float*)(smem + 40960);       // aliases Vs, post-loop only

    const int bid = blockIdx.x;
    const int hq_ = bid & 3;
    const int jt = (bid >> 2) & 31;
    const int b = bid >> 7;
    const int h_base = hq_ * 64;
    const int j_base = jt * 16;
    const int t = threadIdx.x;
    const int lane = t & 63;
    const int w = t >> 6;
    const int q = lane >> 4;
    const int l15 = lane & 15;

    const __half* Vb = V + (size_t)b * Nq * Hq;
    const float* adjb = adj + (size_t)b * Nq * Nq;

    const int srow = t >> 4;
    const int sc0 = (t & 15) * 2;

    {
        const int n = t & 63;
        const int swz = n & 31;
        for (int kk = (t >> 6); kk < 256; kk += 4) {
            float val = We2[kk * 256 + h_base + n];
            Wt[n * 256 + ((((kk >> 3) ^ swz)) << 3) + (kk & 7)] = __float2half(val);
        }
    }
    {
        const uint4* gp = (const uint4*)(U + (size_t)(b * Nq + j_base + srow) * Hq);
        uint4 v0 = gp[sc0];
        uint4 v1 = gp[sc0 + 1];
        *(uint4*)&Us[srow * 256 + ((sc0 ^ srow) << 3)] = v0;
        *(uint4*)&Us[srow * 256 + (((sc0 + 1) ^ srow) << 3)] = v1;
    }

    float bias[4];
#pragma unroll
    for (int nt = 0; nt < 4; ++nt) bias[nt] = be2[h_base + nt * 16 + l15];

    f32x4 agg[4];
#pragma unroll
    for (int nt = 0; nt < 4; ++nt) agg[nt] = (f32x4){0.f, 0.f, 0.f, 0.f};

    uint4 pva, pvb; float pad_;
    {
        const uint4* gp = (const uint4*)(Vb + (size_t)(0 + srow) * Hq);
        pva = gp[sc0]; pvb = gp[sc0 + 1];
        pad_ = adjb[(size_t)(0 + srow) * Nq + j_base + (t & 15)];
        *(uint4*)&Vs[0 * 4096 + srow * 256 + ((sc0 ^ srow) << 3)] = pva;
        *(uint4*)&Vs[0 * 4096 + srow * 256 + (((sc0 + 1) ^ srow) << 3)] = pvb;
        adjs[0 * 256 + t] = pad_;
    }
    {
        const uint4* gp = (const uint4*)(Vb + (size_t)(16 + srow) * Hq);
        pva = gp[sc0]; pvb = gp[sc0 + 1];
        pad_ = adjb[(size_t)(16 + srow) * Nq + j_base + (t & 15)];
    }
    __syncthreads();

    for (int ch = 0; ch < 32; ++ch) {
        const int cur = ch & 1;
        const __half* Vcur = Vs + cur * 4096;
        const float* Acur = adjs + cur * 256;

        f32x4 acc[4][4];
#pragma unroll
        for (int mi = 0; mi < 4; ++mi)
#pragma unroll
            for (int nt = 0; nt < 4; ++nt)
                acc[mi][nt] = (f32x4){bias[nt], bias[nt], bias[nt], bias[nt]};

#pragma unroll
        for (int ks = 0; ks < 8; ++ks) {
            const int c = ks * 4 + q;
            const f16x8 uvec = *(const f16x8*)&Us[l15 * 256 + ((c ^ l15) << 3)];
            f16x8 afrag[4];
#pragma unroll
            for (int mi = 0; mi < 4; ++mi) {
                const int iv = w * 4 + mi;
                const f16x8 vvec = *(const f16x8*)&Vcur[iv * 256 + ((c ^ iv) << 3)];
                afrag[mi] = hadd_relu(uvec, vvec);
            }
            f16x8 bf[4];
#pragma unroll
            for (int nt = 0; nt < 4; ++nt) {
                const int rn = nt * 16 + l15;
                bf[nt] = *(const f16x8*)&Wt[rn * 256 + ((c ^ (rn & 31)) << 3)];
            }
#pragma unroll
            for (int mi = 0; mi < 4; ++mi)
#pragma unroll
                for (int nt = 0; nt < 4; ++nt)
                    acc[mi][nt] = __builtin_amdgcn_mfma_f32_16x16x32_f16(
                        afrag[mi], bf[nt], acc[mi][nt], 0, 0, 0);
        }

#pragma unroll
        for (int mi = 0; mi < 4; ++mi) {
            const int iv = w * 4 + mi;
            const f32x4 av = *(const f32x4*)&Acur[iv * 16 + q * 4];
#pragma unroll
            for (int nt = 0; nt < 4; ++nt) {
                agg[nt][0] = fmaf(av[0], fmaxf(acc[mi][nt][0], 0.f), agg[nt][0]);
                agg[nt][1] = fmaf(av[1], fmaxf(acc[mi][nt][1], 0.f), agg[nt][1]);
                agg[nt][2] = fmaf(av[2], fmaxf(acc[mi][nt][2], 0.f), agg[nt][2]);
                agg[nt][3] = fmaf(av[3], fmaxf(acc[mi][nt][3], 0.f), agg[nt][3]);
            }
        }

        if (ch < 31) {
            const int nxt = cur ^ 1;
            *(uint4*)&Vs[nxt * 4096 + srow * 256 + ((sc0 ^ srow) << 3)] = pva;
            *(uint4*)&Vs[nxt * 4096 + srow * 256 + (((sc0 + 1) ^ srow) << 3)] = pvb;
            adjs[nxt * 256 + t] = pad_;
            if (ch < 30) {
                const int i_base = (ch + 2) * 16;
                const uint4* gp = (const uint4*)(Vb + (size_t)(i_base + srow) * Hq);
                pva = gp[sc0]; pvb = gp[sc0 + 1];
                pad_ = adjb[(size_t)(i_base + srow) * Nq + j_base + (t & 15)];
            }
        }
        __syncthreads();
    }

#pragma unroll
    for (int nt = 0; nt < 4; ++nt)
#pragma unroll
        for (int r = 0; r < 4; ++r)
            red[w * 1024 + (q * 4 + r) * 64 + nt * 16 + l15] = agg[nt][r];
    __syncthreads();
    {
        const int j = t >> 4;
        const int h0 = (t & 15) * 4;
        f32x4 s = *(const f32x4*)&red[0 * 1024 + j * 64 + h0];
        s += *(const f32x4*)&red[1 * 1024 + j * 64 + h0];
        s += *(const f32x4*)&red[2 * 1024 + j * 64 + h0];
        s += *(const f32x4*)&red[3 * 1024 + j * 64 + h0];
        *(f32x4*)&aggws[(size_t)(b * Nq + j_base + j) * Hq + h_base + h0] = s;
    }

    // ---- ticket: 4th finisher of group (b,jt) runs the tail for 16 nodes --
    __threadfence();                               // release aggws stores
    if (t == 0) ticket_s = atomicAdd(&counters[bid >> 2], 1);
    __syncthreads();                               // ticket visible; red reads done
    if (ticket_s != 3) return;
    __threadfence();                               // acquire peers' aggws stores

    // ================= tail phase (R11 body): nodes g0..g0+15 =============
    {
        __half* actA = (__half*)smem;              // 8 KB
        __half* actB = (__half*)(smem + 8192);     // 8 KB
        float* xs = (float*)(smem + 16384);        // [16][4]
        float* part = (float*)(smem + 16640);      // [4][16][4]
        float* s5 = (float*)(smem + 17664);        // [16][4]
        const int g0 = (bid >> 2) * 16;            // = b*512 + jt*16
        const int hb = w * 64;

        {
            const int row = t >> 4;
            const int g = (t & 15) * 2;
            const float* src = aggws + (size_t)(g0 + row) * 256;
            *(uint4*)&actA[row * 256 + ((g ^ row) << 3)] = cvt8h(src + g * 8);
            *(uint4*)&actA[row * 256 + (((g + 1) ^ row) << 3)] = cvt8h(src + g * 8 + 8);
        }
        if (t < 64) xs[(t >> 2) * 4 + (t & 3)] = x[(size_t)(g0 + (t >> 2)) * 4 + (t & 3)];
        __syncthreads();

        f32x4 acc[4];
        // layer n1
#pragma unroll
        for (int nt = 0; nt < 4; ++nt) {
            const float bv = bn1[hb + nt * 16 + l15];
            acc[nt] = (f32x4){bv, bv, bv, bv};
        }
#pragma unroll
        for (int ks = 0; ks < 8; ++ks) {
            const int c = ks * 4 + q;
            const f16x8 af = *(const f16x8*)&actA[l15 * 256 + ((c ^ l15) << 3)];
#pragma unroll
            for (int nt = 0; nt < 4; ++nt) {
                const f16x8 bf = *(const f16x8*)&Wt16[(size_t)(hb + nt * 16 + l15) * 256 + c * 8];
                acc[nt] = __builtin_amdgcn_mfma_f32_16x16x32_f16(af, bf, acc[nt], 0, 0, 0);
            }
        }
#pragma unroll
        for (int nt = 0; nt < 4; ++nt) {
            const int n = hb + nt * 16 + l15;
            const int g = n >> 3;
#pragma unroll
            for (int r = 0; r < 4; ++r) {
                const int row = q * 4 + r;
                actB[row * 256 + ((g ^ row) << 3) + (n & 7)] = __float2half(fmaxf(acc[nt][r], 0.f));
            }
        }
        __syncthreads();

        // layer n2
#pragma unroll
        for (int nt = 0; nt < 4; ++nt) {
            const float bv = bn2[hb + nt * 16 + l15];
            acc[nt] = (f32x4){bv, bv, bv, bv};
        }
#pragma unroll
        for (int ks = 0; ks < 8; ++ks) {
            const int c = ks * 4 + q;
            const f16x8 af = *(const f16x8*)&actB[l15 * 256 + ((c ^ l15) << 3)];
#pragma unroll
            for (int nt = 0; nt < 4; ++nt) {
                const f16x8 bf = *(const f16x8*)&Wt16[65536 + (size_t)(hb + nt * 16 + l15) * 256 + c * 8];
                acc[nt] = __builtin_amdgcn_mfma_f32_16x16x32_f16(af, bf, acc[nt], 0, 0, 0);
            }
        }
#pragma unroll
        for (int nt = 0; nt < 4; ++nt) {
            const int n = hb + nt * 16 + l15;
            const int g = n >> 3;
#pragma unroll
            for (int r = 0; r < 4; ++r) {
                const int row = q * 4 + r;
                actA[row * 256 + ((g ^ row) << 3) + (n & 7)] = __float2half(fmaxf(acc[nt][r], 0.f));
            }
        }
        __syncthreads();

        // layer o1 (x-part folded into init; no relu)
#pragma unroll
        for (int nt = 0; nt < 4; ++nt) {
            const int n = hb + nt * 16 + l15;
            const float bv = bo1[n];
            const float w0 = Wo1[0 * 256 + n], w1 = Wo1[1 * 256 + n];
            const float w2 = Wo1[2 * 256 + n], w3 = Wo1[3 * 256 + n];
#pragma unroll
            for (int r = 0; r < 4; ++r) {
                const int row = q * 4 + r;
                float v = bv;
                v = fmaf(xs[row * 4 + 0], w0, v); v = fmaf(xs[row * 4 + 1], w1, v);
                v = fmaf(xs[row * 4 + 2], w2, v); v = fmaf(xs[row * 4 + 3], w3, v);
                acc[nt][r] = v;
            }
        }
#pragma unroll
        for (int ks = 0; ks < 8; ++ks) {
            const int c = ks * 4 + q;
            const f16x8 af = *(const f16x8*)&actA[l15 * 256 + ((c ^ l15) << 3)];
#pragma unroll
            for (int nt = 0; nt < 4; ++nt) {
                const f16x8 bf = *(const f16x8*)&Wt16[2 * 65536 + (size_t)(hb + nt * 16 + l15) * 256 + c * 8];
                acc[nt] = __builtin_amdgcn_mfma_f32_16x16x32_f16(af, bf, acc[nt], 0, 0, 0);
            }
        }

        // layer o + log_softmax
        float p[4][4];
#pragma unroll
        for (int r = 0; r < 4; ++r)
#pragma unroll
            for (int d = 0; d < 4; ++d) p[r][d] = 0.f;
#pragma unroll
        for (int nt = 0; nt < 4; ++nt) {
            const int n = hb + nt * 16 + l15;
            const float4 wv = *(const float4*)&Wo[n * 4];
#pragma unroll
            for (int r = 0; r < 4; ++r) {
                p[r][0] = fmaf(acc[nt][r], wv.x, p[r][0]);
                p[r][1] = fmaf(acc[nt][r], wv.y, p[r][1]);
                p[r][2] = fmaf(acc[nt][r], wv.z, p[r][2]);
                p[r][3] = fmaf(acc[nt][r], wv.w, p[r][3]);
            }
        }
#pragma unroll
        for (int off = 1; off < 16; off <<= 1)
#pragma unroll
            for (int r = 0; r < 4; ++r)
#pragma unroll
                for (int d = 0; d < 4; ++d)
                    p[r][d] += __shfl_xor(p[r][d], off);
        if (l15 == 0) {
#pragma unroll
            for (int r = 0; r < 4; ++r)
#pragma unroll
                for (int d = 0; d < 4; ++d) part[(w * 16 + q * 4 + r) * 4 + d] = p[r][d];
        }
        __syncthreads();
        if (t < 64) {
            const int row = t >> 2;
            const int d = t & 3;
            s5[row * 4 + d] = part[(0 * 16 + row) * 4 + d] + part[(1 * 16 + row) * 4 + d]
                            + part[(2 * 16 + row) * 4 + d] + part[(3 * 16 + row) * 4 + d] + bo[d];
        }
        __syncthreads();
        if (t < 16) {
            const float v0 = s5[t * 4 + 0], v1 = s5[t * 4 + 1];
            const float v2 = s5[t * 4 + 2], v3 = s5[t * 4 + 3];
            const float m = fmaxf(fmaxf(v0, v1), fmaxf(v2, v3));
            const float s = expf(v0 - m) + expf(v1 - m) + expf(v2 - m) + expf(v3 - m);
            const float lse = m + logf(s);
            float* op = out + (size_t)(g0 + t) * 4;
            op[0] = v0 - lse; op[1] = v1 - lse; op[2] = v2 - lse; op[3] = v3 - lse;
        }
    }
}

extern "C" void kernel_launch(void* const* d_in, const int* in_sizes, int n_in,
                              void* d_out, int out_size, void* d_ws, size_t ws_size,
                              hipStream_t stream) {
    const float* x   = (const float*)d_in[0];
    const float* adj = (const float*)d_in[1];
    const float* We1 = (const float*)d_in[2];
    const float* be1 = (const float*)d_in[3];
    const float* We2 = (const float*)d_in[4];
    const float* be2 = (const float*)d_in[5];
    const float* Wn1 = (const float*)d_in[6];
    const float* bn1 = (const float*)d_in[7];
    const float* Wn2 = (const float*)d_in[8];
    const float* bn2 = (const float*)d_in[9];
    const float* Wo1 = (const float*)d_in[10];
    const float* bo1 = (const float*)d_in[11];
    const float* Wo  = (const float*)d_in[12];
    const float* bo  = (const float*)d_in[13];
    float* out = (float*)d_out;

    // ws: U fp16 1MB | V fp16 1MB | agg f32 2MB | Wt16 fp16 384KB | counters 512B
    __half* U = (__half*)d_ws;
    __half* V = U + (size_t)Bq * Nq * Hq;
    float* aggws = (float*)((char*)d_ws + (size_t)2 * Bq * Nq * Hq * sizeof(__half));
    __half* Wt16 = (__half*)((char*)d_ws + (size_t)4 * 1024 * 1024);
    int* counters = (int*)((char*)d_ws + (size_t)4 * 1024 * 1024 + 393216);

    prep_all<<<304, 256, 0, stream>>>(x, We1, be1, U, V, Wn1, Wn2, Wo1, Wt16, counters);
    edge_gemm<<<512, 256, 0, stream>>>(U, V, We2, be2, adj, aggws,
                                       x, Wt16, bn1, bn2, Wo1, bo1, Wo, bo,
                                       out, counters);
}

// Round 15
// 220.166 us; speedup vs baseline: 1.2117x; 1.2117x over previous
//
#include <hip/hip_runtime.h>
#include <hip/hip_fp16.h>
#include <math.h>

#define Bq 4
#define Nq 512
#define Dq 4
#define Hq 256

typedef _Float16 f16x8 __attribute__((ext_vector_type(8)));
typedef float f32x4 __attribute__((ext_vector_type(4)));

// packed fp16 add + relu on 8 halves (v_pk_add_f16 + v_pk_max_f16)
__device__ __forceinline__ f16x8 hadd_relu(f16x8 u, f16x8 v) {
    f16x8 s = u + v;
    const f16x8 z = (f16x8)(_Float16)0.0f;
    return __builtin_elementwise_max(s, z);
}

__device__ __forceinline__ uint4 cvt8h(const float* p) {
    union { __half h[8]; uint4 u; } r;
#pragma unroll
    for (int i = 0; i < 8; ++i) r.h[i] = __float2half(p[i]);
    return r.u;
}

// ---------------- kernel 1: fused prep (U/V + tail-weight transpose) ------
// blocks 0..255: U/V for 8 rows each (grid-stride; replaces 2048 tiny blocks)
// blocks 256..303: coalesced 64x64 LDS-tile transpose of Wn1/Wn2/Wo1[4:]
__global__ __launch_bounds__(256) void prep_all(
    const float* __restrict__ x, const float* __restrict__ We1,
    const float* __restrict__ be1, __half* __restrict__ U, __half* __restrict__ V,
    const float* __restrict__ Wn1, const float* __restrict__ Wn2,
    const float* __restrict__ Wo1, __half* __restrict__ Wt16) {
    const int bid = blockIdx.x;
    const int t = threadIdx.x;
    if (bid < 256) {
        const float w0 = We1[0 * 256 + t], w1 = We1[1 * 256 + t];
        const float w2 = We1[2 * 256 + t], w3 = We1[3 * 256 + t];
        const float w4 = We1[4 * 256 + t], w5 = We1[5 * 256 + t];
        const float w6 = We1[6 * 256 + t], w7 = We1[7 * 256 + t];
        const float bv = be1[t];
#pragma unroll
        for (int r = 0; r < 8; ++r) {
            const int row = bid * 8 + r;
            const float* xp = x + row * Dq;
            const float x0 = xp[0], x1 = xp[1], x2 = xp[2], x3 = xp[3];
            float u = bv;
            u = fmaf(x0, w0, u); u = fmaf(x1, w1, u);
            u = fmaf(x2, w2, u); u = fmaf(x3, w3, u);
            float v = x0 * w4;
            v = fmaf(x1, w5, v); v = fmaf(x2, w6, v); v = fmaf(x3, w7, v);
            U[(size_t)row * Hq + t] = __float2half(u);
            V[(size_t)row * Hq + t] = __float2half(v);
        }
    } else {
        __shared__ float ld[64][65];       // padded: stride-65 reads conflict-free
        const int tid = bid - 256;         // 0..47
        const int mat = tid >> 4;          // 0..2
        const int tile = tid & 15;         // 4x4 tiles of 64x64
        const int k0 = (tile >> 2) * 64;
        const int n0 = (tile & 3) * 64;
        const float* W = (mat == 0) ? Wn1 : (mat == 1) ? Wn2 : (Wo1 + 4 * 256);
        const int rr = t >> 6;             // 0..3
        const int cc = t & 63;             // 0..63
#pragma unroll
        for (int r = 0; r < 16; ++r) {
            const int row = r * 4 + rr;
            ld[row][cc] = W[(size_t)(k0 + row) * 256 + n0 + cc];  // coalesced read
        }
        __syncthreads();
#pragma unroll
        for (int r = 0; r < 16; ++r) {
            const int nrow = r * 4 + rr;
            Wt16[((size_t)mat * 256 + n0 + nrow) * 256 + k0 + cc] =
                __float2half(ld[cc][nrow]);
        }
    }
}

// ---------------- kernel 2: fused edge GEMM + adjacency aggregation --------
// R13 structure (proven best, 145 us). R15 delta: epilogue expressed as
// 4-wide vector max + vector FMA so the compiler can emit packed 2xfp32
// VALU (v_pk_max_f32 / v_pk_fma_f32) — VALU is the busiest pipe (51%).
// R14 lesson: do NOT graft tail code onto this loop (compiler scheduling
// of the hot loop degraded 146->221 us).
__global__ __launch_bounds__(256, 2) void edge_gemm(
    const __half* __restrict__ U, const __half* __restrict__ V,
    const float* __restrict__ We2, const float* __restrict__ be2,
    const float* __restrict__ adj, float* __restrict__ aggws) {
    __shared__ __align__(16) char smem[59392];
    __half* Wt = (__half*)smem;
    __half* Us = (__half*)(smem + 32768);
    __half* Vs = (__half*)(smem + 40960);      // [2][16][256] halves
    float* adjs = (float*)(smem + 57344);      // [2][16][16]
    float* red = (float*)(smem + 40960);       // aliases Vs, post-loop only

    const int bid = blockIdx.x;
    const int hq_ = bid & 3;
    const int jt = (bid >> 2) & 31;
    const int b = bid >> 7;
    const int h_base = hq_ * 64;
    const int j_base = jt * 16;
    const int t = threadIdx.x;
    const int lane = t & 63;
    const int w = t >> 6;
    const int q = lane >> 4;
    const int l15 = lane & 15;

    const __half* Vb = V + (size_t)b * Nq * Hq;
    const float* adjb = adj + (size_t)b * Nq * Nq;

    const int srow = t >> 4;
    const int sc0 = (t & 15) * 2;

    {
        const int n = t & 63;
        const int swz = n & 31;
        for (int kk = (t >> 6); kk < 256; kk += 4) {
            float val = We2[kk * 256 + h_base + n];
            Wt[n * 256 + ((((kk >> 3) ^ swz)) << 3) + (kk & 7)] = __float2half(val);
        }
    }
    {
        const uint4* gp = (const uint4*)(U + (size_t)(b * Nq + j_base + srow) * Hq);
        uint4 v0 = gp[sc0];
        uint4 v1 = gp[sc0 + 1];
        *(uint4*)&Us[srow * 256 + ((sc0 ^ srow) << 3)] = v0;
        *(uint4*)&Us[srow * 256 + (((sc0 + 1) ^ srow) << 3)] = v1;
    }

    float bias[4];
#pragma unroll
    for (int nt = 0; nt < 4; ++nt) bias[nt] = be2[h_base + nt * 16 + l15];

    f32x4 agg[4];
#pragma unroll
    for (int nt = 0; nt < 4; ++nt) agg[nt] = (f32x4){0.f, 0.f, 0.f, 0.f};

    uint4 pva, pvb; float pad_;
    {
        const uint4* gp = (const uint4*)(Vb + (size_t)(0 + srow) * Hq);
        pva = gp[sc0]; pvb = gp[sc0 + 1];
        pad_ = adjb[(size_t)(0 + srow) * Nq + j_base + (t & 15)];
        *(uint4*)&Vs[0 * 4096 + srow * 256 + ((sc0 ^ srow) << 3)] = pva;
        *(uint4*)&Vs[0 * 4096 + srow * 256 + (((sc0 + 1) ^ srow) << 3)] = pvb;
        adjs[0 * 256 + t] = pad_;
    }
    {
        const uint4* gp = (const uint4*)(Vb + (size_t)(16 + srow) * Hq);
        pva = gp[sc0]; pvb = gp[sc0 + 1];
        pad_ = adjb[(size_t)(16 + srow) * Nq + j_base + (t & 15)];
    }
    __syncthreads();

    const f32x4 zero4 = (f32x4){0.f, 0.f, 0.f, 0.f};

    for (int ch = 0; ch < 32; ++ch) {
        const int cur = ch & 1;
        const __half* Vcur = Vs + cur * 4096;
        const float* Acur = adjs + cur * 256;

        f32x4 acc[4][4];
#pragma unroll
        for (int mi = 0; mi < 4; ++mi)
#pragma unroll
            for (int nt = 0; nt < 4; ++nt)
                acc[mi][nt] = (f32x4){bias[nt], bias[nt], bias[nt], bias[nt]};

#pragma unroll
        for (int ks = 0; ks < 8; ++ks) {
            const int c = ks * 4 + q;
            const f16x8 uvec = *(const f16x8*)&Us[l15 * 256 + ((c ^ l15) << 3)];
            f16x8 afrag[4];
#pragma unroll
            for (int mi = 0; mi < 4; ++mi) {
                const int iv = w * 4 + mi;
                const f16x8 vvec = *(const f16x8*)&Vcur[iv * 256 + ((c ^ iv) << 3)];
                afrag[mi] = hadd_relu(uvec, vvec);
            }
            f16x8 bf[4];
#pragma unroll
            for (int nt = 0; nt < 4; ++nt) {
                const int rn = nt * 16 + l15;
                bf[nt] = *(const f16x8*)&Wt[rn * 256 + ((c ^ (rn & 31)) << 3)];
            }
#pragma unroll
            for (int mi = 0; mi < 4; ++mi)
#pragma unroll
                for (int nt = 0; nt < 4; ++nt)
                    acc[mi][nt] = __builtin_amdgcn_mfma_f32_16x16x32_f16(
                        afrag[mi], bf[nt], acc[mi][nt], 0, 0, 0);
        }

        // epilogue: agg[j,h] += adj[i,j] * relu(z) — vector form for pk-f32
#pragma unroll
        for (int mi = 0; mi < 4; ++mi) {
            const int iv = w * 4 + mi;
            const f32x4 av = *(const f32x4*)&Acur[iv * 16 + q * 4];
#pragma unroll
            for (int nt = 0; nt < 4; ++nt) {
                const f32x4 rel = __builtin_elementwise_max(acc[mi][nt], zero4);
                agg[nt] = av * rel + agg[nt];
            }
        }

        if (ch < 31) {
            const int nxt = cur ^ 1;
            *(uint4*)&Vs[nxt * 4096 + srow * 256 + ((sc0 ^ srow) << 3)] = pva;
            *(uint4*)&Vs[nxt * 4096 + srow * 256 + (((sc0 + 1) ^ srow) << 3)] = pvb;
            adjs[nxt * 256 + t] = pad_;
            if (ch < 30) {
                const int i_base = (ch + 2) * 16;
                const uint4* gp = (const uint4*)(Vb + (size_t)(i_base + srow) * Hq);
                pva = gp[sc0]; pvb = gp[sc0 + 1];
                pad_ = adjb[(size_t)(i_base + srow) * Nq + j_base + (t & 15)];
            }
        }
        __syncthreads();
    }

#pragma unroll
    for (int nt = 0; nt < 4; ++nt)
#pragma unroll
        for (int r = 0; r < 4; ++r)
            red[w * 1024 + (q * 4 + r) * 64 + nt * 16 + l15] = agg[nt][r];
    __syncthreads();
    {
        const int j = t >> 4;
        const int h0 = (t & 15) * 4;
        f32x4 s = *(const f32x4*)&red[0 * 1024 + j * 64 + h0];
        s += *(const f32x4*)&red[1 * 1024 + j * 64 + h0];
        s += *(const f32x4*)&red[2 * 1024 + j * 64 + h0];
        s += *(const f32x4*)&red[3 * 1024 + j * 64 + h0];
        *(f32x4*)&aggws[(size_t)(b * Nq + j_base + j) * Hq + h_base + h0] = s;
    }
}

// ---------------- kernel 3: MFMA node-MLP tail + log_softmax --------------
// R11/R13 verbatim: 128 blocks x 16 nodes, per-wave h-slice 64.
__global__ __launch_bounds__(256) void tail_kernel(
    const float* __restrict__ aggws, const float* __restrict__ x,
    const __half* __restrict__ Wt16,
    const float* __restrict__ bn1, const float* __restrict__ bn2,
    const float* __restrict__ Wo1, const float* __restrict__ bo1,
    const float* __restrict__ Wo, const float* __restrict__ bo,
    float* __restrict__ out) {
    __shared__ __align__(16) __half actA[16 * 256];   // 8 KB
    __shared__ __align__(16) __half actB[16 * 256];   // 8 KB
    __shared__ float xs[16][4];
    __shared__ float part[4][16][4];
    __shared__ float s5[16][4];
    const int g0 = blockIdx.x * 16;
    const int t = threadIdx.x;
    const int lane = t & 63;
    const int w = t >> 6;
    const int q = lane >> 4;
    const int l15 = lane & 15;
    const int hb = w * 64;

    {
        const int row = t >> 4;
        const int g = (t & 15) * 2;
        const float* src = aggws + (size_t)(g0 + row) * 256;
        *(uint4*)&actA[row * 256 + ((g ^ row) << 3)] = cvt8h(src + g * 8);
        *(uint4*)&actA[row * 256 + (((g + 1) ^ row) << 3)] = cvt8h(src + g * 8 + 8);
    }
    if (t < 64) xs[t >> 2][t & 3] = x[(size_t)(g0 + (t >> 2)) * 4 + (t & 3)];
    __syncthreads();

    f32x4 acc[4];
    // layer n1
#pragma unroll
    for (int nt = 0; nt < 4; ++nt) {
        const float bv = bn1[hb + nt * 16 + l15];
        acc[nt] = (f32x4){bv, bv, bv, bv};
    }
#pragma unroll
    for (int ks = 0; ks < 8; ++ks) {
        const int c = ks * 4 + q;
        const f16x8 af = *(const f16x8*)&actA[l15 * 256 + ((c ^ l15) << 3)];
#pragma unroll
        for (int nt = 0; nt < 4; ++nt) {
            const f16x8 bf = *(const f16x8*)&Wt16[(size_t)(hb + nt * 16 + l15) * 256 + c * 8];
            acc[nt] = __builtin_amdgcn_mfma_f32_16x16x32_f16(af, bf, acc[nt], 0, 0, 0);
        }
    }
#pragma unroll
    for (int nt = 0; nt < 4; ++nt) {
        const int n = hb + nt * 16 + l15;
        const int g = n >> 3;
#pragma unroll
        for (int r = 0; r < 4; ++r) {
            const int row = q * 4 + r;
            actB[row * 256 + ((g ^ row) << 3) + (n & 7)] = __float2half(fmaxf(acc[nt][r], 0.f));
        }
    }
    __syncthreads();

    // layer n2
#pragma unroll
    for (int nt = 0; nt < 4; ++nt) {
        const float bv = bn2[hb + nt * 16 + l15];
        acc[nt] = (f32x4){bv, bv, bv, bv};
    }
#pragma unroll
    for (int ks = 0; ks < 8; ++ks) {
        const int c = ks * 4 + q;
        const f16x8 af = *(const f16x8*)&actB[l15 * 256 + ((c ^ l15) << 3)];
#pragma unroll
        for (int nt = 0; nt < 4; ++nt) {
            const f16x8 bf = *(const f16x8*)&Wt16[65536 + (size_t)(hb + nt * 16 + l15) * 256 + c * 8];
            acc[nt] = __builtin_amdgcn_mfma_f32_16x16x32_f16(af, bf, acc[nt], 0, 0, 0);
        }
    }
#pragma unroll
    for (int nt = 0; nt < 4; ++nt) {
        const int n = hb + nt * 16 + l15;
        const int g = n >> 3;
#pragma unroll
        for (int r = 0; r < 4; ++r) {
            const int row = q * 4 + r;
            actA[row * 256 + ((g ^ row) << 3) + (n & 7)] = __float2half(fmaxf(acc[nt][r], 0.f));
        }
    }
    __syncthreads();

    // layer o1 (x-part folded into init; no relu)
#pragma unroll
    for (int nt = 0; nt < 4; ++nt) {
        const int n = hb + nt * 16 + l15;
        const float bv = bo1[n];
        const float w0 = Wo1[0 * 256 + n], w1 = Wo1[1 * 256 + n];
        const float w2 = Wo1[2 * 256 + n], w3 = Wo1[3 * 256 + n];
#pragma unroll
        for (int r = 0; r < 4; ++r) {
            const int row = q * 4 + r;
            float v = bv;
            v = fmaf(xs[row][0], w0, v); v = fmaf(xs[row][1], w1, v);
            v = fmaf(xs[row][2], w2, v); v = fmaf(xs[row][3], w3, v);
            acc[nt][r] = v;
        }
    }
#pragma unroll
    for (int ks = 0; ks < 8; ++ks) {
        const int c = ks * 4 + q;
        const f16x8 af = *(const f16x8*)&actA[l15 * 256 + ((c ^ l15) << 3)];
#pragma unroll
        for (int nt = 0; nt < 4; ++nt) {
            const f16x8 bf = *(const f16x8*)&Wt16[2 * 65536 + (size_t)(hb + nt * 16 + l15) * 256 + c * 8];
            acc[nt] = __builtin_amdgcn_mfma_f32_16x16x32_f16(af, bf, acc[nt], 0, 0, 0);
        }
    }

    // layer o + log_softmax
    float p[4][4];
#pragma unroll
    for (int r = 0; r < 4; ++r)
#pragma unroll
        for (int d = 0; d < 4; ++d) p[r][d] = 0.f;
#pragma unroll
    for (int nt = 0; nt < 4; ++nt) {
        const int n = hb + nt * 16 + l15;
        const float4 wv = *(const float4*)&Wo[n * 4];
#pragma unroll
        for (int r = 0; r < 4; ++r) {
            p[r][0] = fmaf(acc[nt][r], wv.x, p[r][0]);
            p[r][1] = fmaf(acc[nt][r], wv.y, p[r][1]);
            p[r][2] = fmaf(acc[nt][r], wv.z, p[r][2]);
            p[r][3] = fmaf(acc[nt][r], wv.w, p[r][3]);
        }
    }
#pragma unroll
    for (int off = 1; off < 16; off <<= 1)
#pragma unroll
        for (int r = 0; r < 4; ++r)
#pragma unroll
            for (int d = 0; d < 4; ++d)
                p[r][d] += __shfl_xor(p[r][d], off);
    if (l15 == 0) {
#pragma unroll
        for (int r = 0; r < 4; ++r)
#pragma unroll
            for (int d = 0; d < 4; ++d) part[w][q * 4 + r][d] = p[r][d];
    }
    __syncthreads();
    if (t < 64) {
        const int row = t >> 2;
        const int d = t & 3;
        s5[row][d] = part[0][row][d] + part[1][row][d] + part[2][row][d]
                   + part[3][row][d] + bo[d];
    }
    __syncthreads();
    if (t < 16) {
        const float v0 = s5[t][0], v1 = s5[t][1], v2 = s5[t][2], v3 = s5[t][3];
        const float m = fmaxf(fmaxf(v0, v1), fmaxf(v2, v3));
        const float s = expf(v0 - m) + expf(v1 - m) + expf(v2 - m) + expf(v3 - m);
        const float lse = m + logf(s);
        float* op = out + (size_t)(g0 + t) * 4;
        op[0] = v0 - lse; op[1] = v1 - lse; op[2] = v2 - lse; op[3] = v3 - lse;
    }
}

extern "C" void kernel_launch(void* const* d_in, const int* in_sizes, int n_in,
                              void* d_out, int out_size, void* d_ws, size_t ws_size,
                              hipStream_t stream) {
    const float* x   = (const float*)d_in[0];
    const float* adj = (const float*)d_in[1];
    const float* We1 = (const float*)d_in[2];
    const float* be1 = (const float*)d_in[3];
    const float* We2 = (const float*)d_in[4];
    const float* be2 = (const float*)d_in[5];
    const float* Wn1 = (const float*)d_in[6];
    const float* bn1 = (const float*)d_in[7];
    const float* Wn2 = (const float*)d_in[8];
    const float* bn2 = (const float*)d_in[9];
    const float* Wo1 = (const float*)d_in[10];
    const float* bo1 = (const float*)d_in[11];
    const float* Wo  = (const float*)d_in[12];
    const float* bo  = (const float*)d_in[13];
    float* out = (float*)d_out;

    // ws: U fp16 1MB | V fp16 1MB | agg f32 2MB | Wt16 fp16 384KB
    __half* U = (__half*)d_ws;
    __half* V = U + (size_t)Bq * Nq * Hq;
    float* aggws = (float*)((char*)d_ws + (size_t)2 * Bq * Nq * Hq * sizeof(__half));
    __half* Wt16 = (__half*)((char*)d_ws + (size_t)4 * 1024 * 1024);

    prep_all<<<304, 256, 0, stream>>>(x, We1, be1, U, V, Wn1, Wn2, Wo1, Wt16);
    edge_gemm<<<512, 256, 0, stream>>>(U, V, We2, be2, adj, aggws);
    tail_kernel<<<128, 256, 0, stream>>>(aggws, x, Wt16, bn1, bn2, Wo1, bo1, Wo, bo, out);
}